// Round 9
// baseline (3984.505 us; speedup 1.0000x reference)
//
#include <hip/hip_runtime.h>
#include <float.h>
#include <math.h>

// Problem constants
#define B_ 16
#define N_ 4096
#define S_ 1024
#define K_ 32
#define CIN0 67              // 3 + 64
#define NBS (B_ * S_)        // 16384
#define NEWXYZ_FLOATS (B_ * S_ * 3)  // 49152
#define AST 68               // LDS activation row stride

// ---------------- helpers ----------------

__device__ __forceinline__ float sqdist3(float x, float y, float z,
                                         float cx, float cy, float cz) {
#pragma clang fp contract(off)
  float dx = x - cx, dy = y - cy, dz = z - cz;
  float s = dx * dx;
  s = s + dy * dy;
  s = s + dz * dz;
  return s;
}

__device__ __forceinline__ float knn_dist(float c2, float cx, float cy, float cz,
                                          float x, float y, float z) {
#pragma clang fp contract(off)
  float dot = cx * x; dot = dot + cy * y; dot = dot + cz * z;
  float x2 = x * x;   x2 = x2 + y * y;   x2 = x2 + z * z;
  float d = c2 - 2.0f * dot;
  d = d + x2;
  return d;
}

// ---- DPP cross-lane (gfx9: row_shr:N=0x110|N, row_bcast15=0x142, row_bcast31=0x143) ----
template <int CTRL>
__device__ __forceinline__ float dpp_f(float v, float oldv) {
  return __int_as_float(__builtin_amdgcn_update_dpp(
      __float_as_int(oldv), __float_as_int(v), CTRL, 0xF, 0xF, false));
}
template <int CTRL>
__device__ __forceinline__ int dpp_i(int v, int oldv) {
  return __builtin_amdgcn_update_dpp(oldv, v, CTRL, 0xF, 0xF, false);
}

// argmax combine carrying (val, origIdx, physIdx); tie -> smaller origIdx.
// invalid lanes see val=-1 (< any dist >= 0)
template <int CTRL>
__device__ __forceinline__ void fps_combine3(float& val, int& orig, int& phys) {
  const float tv = dpp_f<CTRL>(val, -1.0f);
  const int to = dpp_i<CTRL>(orig, 0x7fffffff);
  const int tp = dpp_i<CTRL>(phys, 0);
  const bool take = (tv > val) || (tv == val && to < orig);
  val = take ? tv : val;
  orig = take ? to : orig;
  phys = take ? tp : phys;
}

// ---------------- Spatial sort: one block per batch ----------------
// 8x8x8 grid over fixed [-4,4]^3 (gaussian data), counting sort.
// Atomic order nondeterminism only permutes points WITHIN groups; FPS result
// is grouping-independent (pruning is conservative-exact, argmax tie-breaks
// by original index), so d_out is unaffected.
// Physical layout: phys = ((pos&15)<<8)|(pos>>4), so thread t of fps owns
// sorted positions [16t,16t+16) (spatially local) while its LDS reads
// sp[j*256+t] stay lane-consecutive (conflict-free).
__global__ __launch_bounds__(256) void sort_kernel(
    const float* __restrict__ xyz, float4* __restrict__ sortedC,
    int* __restrict__ sortedI) {
  const int b = blockIdx.x;
  const int t = threadIdx.x;
  __shared__ int hist[512];
  __shared__ int scano[512];
  __shared__ int tmp[256];
  const float* xb = xyz + (size_t)b * N_ * 3;
  hist[t] = 0; hist[t + 256] = 0;
  __syncthreads();
  // histogram
  for (int j = 0; j < 16; ++j) {
    const int p = j * 256 + t;
    const float x = xb[p * 3 + 0], y = xb[p * 3 + 1], z = xb[p * 3 + 2];
    int qx = (int)floorf(x + 4.0f); qx = min(max(qx, 0), 7);
    int qy = (int)floorf(y + 4.0f); qy = min(max(qy, 0), 7);
    int qz = (int)floorf(z + 4.0f); qz = min(max(qz, 0), 7);
    atomicAdd(&hist[(qx << 6) | (qy << 3) | qz], 1);
  }
  __syncthreads();
  // exclusive scan over 512 cells (pairwise + Hillis-Steele over 256)
  const int a0 = hist[2 * t], a1 = hist[2 * t + 1];
  const int spair = a0 + a1;
  tmp[t] = spair;
  __syncthreads();
  for (int off = 1; off < 256; off <<= 1) {
    const int v = (t >= off) ? tmp[t - off] : 0;
    __syncthreads();
    tmp[t] += v;
    __syncthreads();
  }
  const int base = tmp[t] - spair;
  scano[2 * t] = base;
  scano[2 * t + 1] = base + a0;
  __syncthreads();
  // scatter
  for (int j = 0; j < 16; ++j) {
    const int p = j * 256 + t;
    const float x = xb[p * 3 + 0], y = xb[p * 3 + 1], z = xb[p * 3 + 2];
    int qx = (int)floorf(x + 4.0f); qx = min(max(qx, 0), 7);
    int qy = (int)floorf(y + 4.0f); qy = min(max(qy, 0), 7);
    int qz = (int)floorf(z + 4.0f); qz = min(max(qz, 0), 7);
    const int cell = (qx << 6) | (qy << 3) | qz;
    const int pos = atomicAdd(&scano[cell], 1);
    const int phys = ((pos & 15) << 8) | (pos >> 4);
    sortedC[(size_t)b * N_ + phys] = make_float4(x, y, z, 0.0f);
    sortedI[(size_t)b * N_ + phys] = p;
  }
}

// ---------------- FPS with exact group pruning ----------------
// 256 thr = 4 waves / batch. Thread group = 16 spatially-local points.
// Per step: triangle-inequality skip test (conservative, margin 1e-3 >> fp
// rounding -> never wrongly skips); active groups do a load-batched 16-pt
// update; wave argmax over per-group maxima via DPP; 1 barrier; resolve.
// Selection identical to numpy: contract(off) distances, first-(original-)
// index tie-break everywhere.
__global__ __launch_bounds__(256, 1) void fps_kernel(
    const float* __restrict__ xyz, const float4* __restrict__ sortedC,
    const int* __restrict__ sortedI, float* __restrict__ newxyz) {
  const int b = blockIdx.x;
  const int t = threadIdx.x;
  __shared__ float4 sp[N_];      // 64 KB sorted coords
  __shared__ int sidx[N_];       // 16 KB original indices
  __shared__ float4 rec[2][4];   // [parity][wave] = (val, origBits, physBits, _)
  const float* xb = xyz + (size_t)b * N_ * 3;
  for (int i = t; i < N_; i += 256) {
    sp[i] = sortedC[(size_t)b * N_ + i];
    sidx[i] = sortedI[(size_t)b * N_ + i];
  }
  __syncthreads();
  // group bounding sphere (centroid + conservative radius)
  float gcx = 0.f, gcy = 0.f, gcz = 0.f;
#pragma unroll
  for (int j = 0; j < 16; ++j) {
    const float4 p = sp[j * 256 + t];
    gcx += p.x; gcy += p.y; gcz += p.z;
  }
  gcx *= 0.0625f; gcy *= 0.0625f; gcz *= 0.0625f;
  float r2 = 0.f;
#pragma unroll
  for (int j = 0; j < 16; ++j) {
    const float4 p = sp[j * 256 + t];
    r2 = fmaxf(r2, sqdist3(p.x, p.y, p.z, gcx, gcy, gcz));
  }
  const float grad = sqrtf(r2) * 1.001f + 1e-5f;
  float dist[16];
#pragma unroll
  for (int j = 0; j < 16; ++j) dist[j] = 1e10f;
  float gv = 1e10f;             // group running max (val)
  int go = 0x7fffffff, gp = t;  // its original + physical index
  float cx = xb[0], cy = xb[1], cz = xb[2];  // farthest init = point 0
  for (int s = 0; s < S_; ++s) {
    if (t == 0) {
      float* o = newxyz + ((size_t)b * S_ + s) * 3;
      o[0] = cx; o[1] = cy; o[2] = cz;
    }
    // conservative skip test: if lb^2*(1-1e-3) >= gmax, no point can update
    const float dgc = sqdist3(gcx, gcy, gcz, cx, cy, cz);
    const float lbr = sqrtf(dgc) - grad;
    const bool act = !(lbr > 0.0f && lbr * lbr * 0.999f >= gv);
    if (act) {
      // batched independent loads + distances
      float ddv[16];
      int ojv[16];
#pragma unroll
      for (int j = 0; j < 16; ++j) {
        const int ph = j * 256 + t;
        const float4 p = sp[ph];
        ddv[j] = sqdist3(p.x, p.y, p.z, cx, cy, cz);
        ojv[j] = sidx[ph];
      }
      __builtin_amdgcn_sched_barrier(0);
      // register-only update + group argmax (tie -> smaller orig idx)
      float nv = -1.0f;
      int no = 0x7fffffff, np = 0;
#pragma unroll
      for (int j = 0; j < 16; ++j) {
        const float nd = fminf(dist[j], ddv[j]);
        dist[j] = nd;
        const bool take = (nd > nv) || (nd == nv && ojv[j] < no);
        nv = take ? nd : nv;
        no = take ? ojv[j] : no;
        np = take ? (j * 256 + t) : np;
      }
      gv = nv; go = no; gp = np;
    }
    // wave argmax over the 64 group maxima
    float v = gv;
    int o = go, ph = gp;
    fps_combine3<0x111>(v, o, ph);
    fps_combine3<0x112>(v, o, ph);
    fps_combine3<0x114>(v, o, ph);
    fps_combine3<0x118>(v, o, ph);
    fps_combine3<0x142>(v, o, ph);
    fps_combine3<0x143>(v, o, ph);
    const float wv = __int_as_float(__builtin_amdgcn_readlane(__float_as_int(v), 63));
    const int wo = __builtin_amdgcn_readlane(o, 63);
    const int wp = __builtin_amdgcn_readlane(ph, 63);
    const int par = s & 1;
    if ((t & 63) == 0) {
      rec[par][t >> 6] = make_float4(wv, __int_as_float(wo), __int_as_float(wp), 0.f);
    }
    __syncthreads();
    // resolve 4 wave candidates (redundant broadcast reads)
    float4 r0 = rec[par][0];
    float bv = r0.x;
    int bo = __float_as_int(r0.y);
    int bp = __float_as_int(r0.z);
#pragma unroll
    for (int w = 1; w < 4; ++w) {
      const float4 r = rec[par][w];
      const int io = __float_as_int(r.y);
      const bool take = (r.x > bv) || (r.x == bv && io < bo);
      bv = take ? r.x : bv;
      bo = take ? io : bo;
      bp = take ? __float_as_int(r.z) : bp;
    }
    const float4 c = sp[bp];  // broadcast read of new centroid
    cx = c.x; cy = c.y; cz = c.z;
  }
}

// ---------------- KNN: one wave per query, 4 queries/block ----------------
__global__ __launch_bounds__(256, 2) void knn_kernel(
    const float* __restrict__ xyz, const float* __restrict__ newxyz,
    int* __restrict__ knn_idx) {
  const int bs0 = blockIdx.x * 4;
  const int b = bs0 >> 10;
  const int t = threadIdx.x;
  const int wave = t >> 6;
  const int lane = t & 63;
  __shared__ float sxx[N_];
  __shared__ float sxy[N_];
  __shared__ float sxz[N_];
  const float* xb = xyz + (size_t)b * N_ * 3;
  for (int p = t; p < N_; p += 256) {
    sxx[p] = xb[p * 3 + 0];
    sxy[p] = xb[p * 3 + 1];
    sxz[p] = xb[p * 3 + 2];
  }
  __syncthreads();
  const int bs = bs0 + wave;
  const float cx = newxyz[(size_t)bs * 3 + 0];
  const float cy = newxyz[(size_t)bs * 3 + 1];
  const float cz = newxyz[(size_t)bs * 3 + 2];
  float c2;
  {
#pragma clang fp contract(off)
    float s = cx * cx;
    s = s + cy * cy;
    s = s + cz * cz;
    c2 = s;
  }
  float d[64];
  float gval[8];
  int gidx[8];
#pragma unroll
  for (int g = 0; g < 8; ++g) {
    float gvv = FLT_MAX;
    int gi = g * 8;
#pragma unroll
    for (int q = 0; q < 8; ++q) {
      const int j = g * 8 + q;
      const int p = j * 64 + lane;
      const float dd = knn_dist(c2, cx, cy, cz, sxx[p], sxy[p], sxz[p]);
      d[j] = dd;
      if (dd < gvv) { gvv = dd; gi = j; }
    }
    gval[g] = gvv; gidx[g] = gi;
  }
  int* krow = knn_idx + (size_t)bs * K_;
  for (int it = 0; it < K_; ++it) {
    float best = gval[0];
    int bj = gidx[0];
#pragma unroll
    for (int g = 1; g < 8; ++g) {
      if (gval[g] < best || (gval[g] == best && gidx[g] < bj)) { best = gval[g]; bj = gidx[g]; }
    }
    int bidx = bj * 64 + lane;
#pragma unroll
    for (int off = 32; off >= 1; off >>= 1) {
      const float ov = __shfl_xor(best, off);
      const int oi = __shfl_xor(bidx, off);
      if (ov < best || (ov == best && oi < bidx)) { best = ov; bidx = oi; }
    }
    if (lane == 0) krow[it] = bidx;
    if (lane == (bidx & 63)) {
      const int jl = bidx >> 6;
      const int gg = jl >> 3;
      const int qq = jl & 7;
#pragma unroll
      for (int g = 0; g < 8; ++g) {
        if (g == gg) {
#pragma unroll
          for (int q = 0; q < 8; ++q) {
            d[g * 8 + q] = (q == qq) ? FLT_MAX : d[g * 8 + q];
          }
          float gvv = FLT_MAX;
          int gi = g * 8;
#pragma unroll
          for (int q = 0; q < 8; ++q) {
            const int j = g * 8 + q;
            if (d[j] < gvv) { gvv = d[j]; gi = j; }
          }
          gval[g] = gvv; gidx[g] = gi;
        }
      }
    }
  }
}

// ---------------- MLP pass building blocks (round-6 proven versions) ----------------

__device__ __forceinline__ void loadw(float* __restrict__ wbuf,
                                      const float* __restrict__ w, int n, int t) {
  for (int i = t; i < n; i += 256) wbuf[i] = w[i];
}

__device__ __forceinline__ void loadw_half(float* __restrict__ wbuf,
                                           const float* __restrict__ w2, int ofs, int t) {
  for (int i = t; i < 64 * 64; i += 256) {
    const int c = i >> 6, j = i & 63;
    wbuf[i] = w2[c * 128 + ofs + j];
  }
}

__device__ __forceinline__ void build_x0(float* __restrict__ act,
    const float* __restrict__ xyz, const float* __restrict__ points,
    const int* __restrict__ knn_idx, const float* __restrict__ newxyz,
    int bs, int t) {
  const int b = bs >> 10;
  const int* krow = knn_idx + (size_t)bs * K_;
  const float cx = newxyz[(size_t)bs * 3 + 0];
  const float cy = newxyz[(size_t)bs * 3 + 1];
  const float cz = newxyz[(size_t)bs * 3 + 2];
  for (int i = t; i < K_ * CIN0; i += 256) {
    const int k = i / CIN0;
    const int c = i - k * CIN0;
    const int p = krow[k];
    float v;
    if (c < 3) {
      v = xyz[((size_t)b * N_ + p) * 3 + c] - (c == 0 ? cx : (c == 1 ? cy : cz));
    } else {
      v = points[((size_t)b * N_ + p) * 64 + (c - 3)];
    }
    act[k * AST + c] = v;
  }
}

template <int CIN>
__device__ __forceinline__ void matmul64(const float* __restrict__ act,
    const float* __restrict__ wbuf, const float* __restrict__ bias,
    float* __restrict__ out, int t) {
  const int k = t >> 3;
  const int g = t & 7;
  float acc[8];
#pragma unroll
  for (int j = 0; j < 8; ++j) acc[j] = bias[g * 8 + j];
  for (int c = 0; c < CIN; ++c) {
    const float xv = act[k * AST + c];
#pragma unroll
    for (int j = 0; j < 8; ++j) acc[j] += xv * wbuf[c * 64 + g * 8 + j];
  }
#pragma unroll
  for (int j = 0; j < 8; ++j) out[k * AST + g * 8 + j] = acc[j];
}

__device__ __forceinline__ void norm_relu64(float* __restrict__ act,
    const float* __restrict__ scale, const float* __restrict__ shift, int t) {
  for (int i = t; i < K_ * 64; i += 256) {
    const int k = i >> 6, c = i & 63;
    const float v = act[k * AST + c] * scale[c] + shift[c];
    act[k * AST + c] = fmaxf(v, 0.0f);
  }
}

__device__ __forceinline__ void stats64(const float* __restrict__ out,
    float* __restrict__ psum, float* __restrict__ psq, int bs, int ofs, int t) {
  if (t < 64) {
    float s = 0.f, q = 0.f;
    for (int k = 0; k < K_; ++k) {
      const float v = out[k * AST + t];
      s += v; q += v * v;
    }
    psum[(size_t)bs * 128 + ofs + t] = s;
    psq[(size_t)bs * 128 + ofs + t] = q;
  }
}

__device__ __forceinline__ void minmax64(const float* __restrict__ out,
    float* __restrict__ maxraw, float* __restrict__ minbuf, int bs, int ofs, int t) {
  if (t >= 64 && t < 128) {
    const int ch = t - 64;
    float mx = -FLT_MAX, mn = FLT_MAX;
    for (int k = 0; k < K_; ++k) {
      const float v = out[k * AST + ch];
      mx = fmaxf(mx, v); mn = fminf(mn, v);
    }
    maxraw[(size_t)bs * 128 + ofs + ch] = mx;
    minbuf[(size_t)bs * 128 + ofs + ch] = mn;
  }
}

// ---------------- Pass A ----------------
__global__ __launch_bounds__(256) void passA_kernel(
    const float* __restrict__ xyz, const float* __restrict__ points,
    const float* __restrict__ newxyz, const int* __restrict__ knn_idx,
    const float* __restrict__ w0, const float* __restrict__ b0,
    float* __restrict__ psum, float* __restrict__ psq) {
  __shared__ float actA[K_ * AST];
  __shared__ float outB[K_ * AST];
  __shared__ float wbuf[CIN0 * 64];
  const int bs = blockIdx.x, t = threadIdx.x;
  build_x0(actA, xyz, points, knn_idx, newxyz, bs, t);
  loadw(wbuf, w0, CIN0 * 64, t);
  __syncthreads();
  matmul64<CIN0>(actA, wbuf, b0, outB, t);
  __syncthreads();
  stats64(outB, psum, psq, bs, 0, t);
}

// ---------------- Pass B ----------------
__global__ __launch_bounds__(256) void passB_kernel(
    const float* __restrict__ xyz, const float* __restrict__ points,
    const float* __restrict__ newxyz, const int* __restrict__ knn_idx,
    const float* __restrict__ w0, const float* __restrict__ b0,
    const float* __restrict__ w1, const float* __restrict__ b1,
    const float* __restrict__ scales, const float* __restrict__ shifts,
    float* __restrict__ psum, float* __restrict__ psq) {
  __shared__ float actA[K_ * AST];
  __shared__ float outB[K_ * AST];
  __shared__ float wbuf[CIN0 * 64];
  const int bs = blockIdx.x, t = threadIdx.x;
  build_x0(actA, xyz, points, knn_idx, newxyz, bs, t);
  loadw(wbuf, w0, CIN0 * 64, t);
  __syncthreads();
  matmul64<CIN0>(actA, wbuf, b0, outB, t);
  __syncthreads();
  norm_relu64(outB, scales, shifts, t);
  loadw(wbuf, w1, 64 * 64, t);
  __syncthreads();
  matmul64<64>(outB, wbuf, b1, actA, t);
  __syncthreads();
  stats64(actA, psum, psq, bs, 0, t);
}

// ---------------- Pass C ----------------
__global__ __launch_bounds__(256) void passC_kernel(
    const float* __restrict__ xyz, const float* __restrict__ points,
    const float* __restrict__ newxyz, const int* __restrict__ knn_idx,
    const float* __restrict__ w0, const float* __restrict__ b0,
    const float* __restrict__ w1, const float* __restrict__ b1,
    const float* __restrict__ w2, const float* __restrict__ b2,
    const float* __restrict__ scales, const float* __restrict__ shifts,
    float* __restrict__ psum, float* __restrict__ psq,
    float* __restrict__ maxraw, float* __restrict__ minbuf) {
  __shared__ float actA[K_ * AST];
  __shared__ float outB[K_ * AST];
  __shared__ float wbuf[CIN0 * 64];
  const int bs = blockIdx.x, t = threadIdx.x;
  build_x0(actA, xyz, points, knn_idx, newxyz, bs, t);
  loadw(wbuf, w0, CIN0 * 64, t);
  __syncthreads();
  matmul64<CIN0>(actA, wbuf, b0, outB, t);
  __syncthreads();
  norm_relu64(outB, scales, shifts, t);
  loadw(wbuf, w1, 64 * 64, t);
  __syncthreads();
  matmul64<64>(outB, wbuf, b1, actA, t);
  __syncthreads();
  norm_relu64(actA, scales + 128, shifts + 128, t);
  loadw_half(wbuf, w2, 0, t);
  __syncthreads();
  matmul64<64>(actA, wbuf, b2, outB, t);
  __syncthreads();
  stats64(outB, psum, psq, bs, 0, t);
  minmax64(outB, maxraw, minbuf, bs, 0, t);
  loadw_half(wbuf, w2, 64, t);
  __syncthreads();
  matmul64<64>(actA, wbuf, b2 + 64, outB, t);
  __syncthreads();
  stats64(outB, psum, psq, bs, 64, t);
  minmax64(outB, maxraw, minbuf, bs, 64, t);
}

// ---------------- BN finalize ----------------
__global__ __launch_bounds__(256) void finalize_kernel(
    const float* __restrict__ psum, const float* __restrict__ psq,
    const float* __restrict__ g, const float* __restrict__ be,
    float* __restrict__ scale, float* __restrict__ shift) {
  const int ch = blockIdx.x, t = threadIdx.x;
  __shared__ float ss[256];
  __shared__ float sq[256];
  float s = 0.f, q = 0.f;
  for (int p = t; p < NBS; p += 256) {
    s += psum[(size_t)p * 128 + ch];
    q += psq[(size_t)p * 128 + ch];
  }
  ss[t] = s; sq[t] = q;
  __syncthreads();
  for (int off = 128; off >= 1; off >>= 1) {
    if (t < off) { ss[t] += ss[t + off]; sq[t] += sq[t + off]; }
    __syncthreads();
  }
  if (t == 0) {
    const float invN = 1.0f / (float)(B_ * S_ * K_);
    const float mean = ss[0] * invN;
    const float var = sq[0] * invN - mean * mean;
    const float sc = g[ch] / sqrtf(var + 1e-5f);
    scale[ch] = sc;
    shift[ch] = be[ch] - mean * sc;
  }
}

// ---------------- Final ----------------
__global__ __launch_bounds__(256) void final_kernel(
    const float* __restrict__ minbuf, const float* __restrict__ scale,
    const float* __restrict__ shift, float* __restrict__ out) {
  const int i = blockIdx.x * 256 + threadIdx.x;  // < B*S*128
  const int ch = i & 127;
  const float sc = scale[ch], sh = shift[ch];
  const float mx = out[NEWXYZ_FLOATS + i];
  const float mn = minbuf[i];
  const float v = sc * (sc >= 0.f ? mx : mn) + sh;
  out[NEWXYZ_FLOATS + i] = fmaxf(v, 0.f);
}

// ---------------- host ----------------
extern "C" void kernel_launch(void* const* d_in, const int* in_sizes, int n_in,
                              void* d_out, int out_size, void* d_ws, size_t ws_size,
                              hipStream_t stream) {
  const float* xyz = (const float*)d_in[0];
  const float* points = (const float*)d_in[1];
  const float* w0 = (const float*)d_in[2];
  const float* b0 = (const float*)d_in[3];
  const float* g0 = (const float*)d_in[4];
  const float* be0 = (const float*)d_in[5];
  const float* w1 = (const float*)d_in[6];
  const float* b1 = (const float*)d_in[7];
  const float* g1 = (const float*)d_in[8];
  const float* be1 = (const float*)d_in[9];
  const float* w2 = (const float*)d_in[10];
  const float* b2 = (const float*)d_in[11];
  const float* g2 = (const float*)d_in[12];
  const float* be2 = (const float*)d_in[13];
  float* out = (float*)d_out;
  float* newxyz = out;
  float* maxraw = out + NEWXYZ_FLOATS;

  float* ws = (float*)d_ws;
  int* knn_idx = (int*)ws;                   // [0, 2MB)
  float* psum = ws + 524288;
  float* psq = psum + (size_t)NBS * 128;
  float* scales = psq + (size_t)NBS * 128;
  float* shifts = scales + 384;
  float* minbuf = shifts + 384;
  // sorted-point overlay: lives in the psum/psq region, consumed by fps
  // BEFORE passA overwrites psum. (16*4096 float4 = 4MB, + 256KB idx)
  float4* sortedC = (float4*)psum;
  int* sortedI = (int*)(psum + (size_t)16 * N_ * 4);

  sort_kernel<<<B_, 256, 0, stream>>>(xyz, sortedC, sortedI);
  fps_kernel<<<B_, 256, 0, stream>>>(xyz, sortedC, sortedI, newxyz);
  knn_kernel<<<NBS / 4, 256, 0, stream>>>(xyz, newxyz, knn_idx);
  passA_kernel<<<NBS, 256, 0, stream>>>(xyz, points, newxyz, knn_idx, w0, b0, psum, psq);
  finalize_kernel<<<64, 256, 0, stream>>>(psum, psq, g0, be0, scales, shifts);
  passB_kernel<<<NBS, 256, 0, stream>>>(xyz, points, newxyz, knn_idx, w0, b0, w1, b1,
                                        scales, shifts, psum, psq);
  finalize_kernel<<<64, 256, 0, stream>>>(psum, psq, g1, be1, scales + 128, shifts + 128);
  passC_kernel<<<NBS, 256, 0, stream>>>(xyz, points, newxyz, knn_idx, w0, b0, w1, b1, w2, b2,
                                        scales, shifts, psum, psq, maxraw, minbuf);
  finalize_kernel<<<128, 256, 0, stream>>>(psum, psq, g2, be2, scales + 256, shifts + 256);
  final_kernel<<<(B_ * S_ * 128) / 256, 256, 0, stream>>>(minbuf, scales + 256,
                                                          shifts + 256, out);
}

// Round 10
// 2696.127 us; speedup vs baseline: 1.4779x; 1.4779x over previous
//
#include <hip/hip_runtime.h>
#include <float.h>
#include <math.h>

// Problem constants
#define B_ 16
#define N_ 4096
#define S_ 1024
#define K_ 32
#define CIN0 67              // 3 + 64
#define NBS (B_ * S_)        // 16384
#define NEWXYZ_FLOATS (B_ * S_ * 3)  // 49152
#define AST 68               // LDS activation row stride

// ---------------- helpers ----------------

__device__ __forceinline__ float sqdist3(float x, float y, float z,
                                         float cx, float cy, float cz) {
#pragma clang fp contract(off)
  float dx = x - cx, dy = y - cy, dz = z - cz;
  float s = dx * dx;
  s = s + dy * dy;
  s = s + dz * dz;
  return s;
}

__device__ __forceinline__ float knn_dist(float c2, float cx, float cy, float cz,
                                          float x, float y, float z) {
#pragma clang fp contract(off)
  float dot = cx * x; dot = dot + cy * y; dot = dot + cz * z;
  float x2 = x * x;   x2 = x2 + y * y;   x2 = x2 + z * z;
  float d = c2 - 2.0f * dot;
  d = d + x2;
  return d;
}

// ---- DPP cross-lane (gfx9: row_shr:N=0x110|N, row_bcast15=0x142, row_bcast31=0x143) ----
template <int CTRL>
__device__ __forceinline__ float dpp_f(float v, float oldv) {
  return __int_as_float(__builtin_amdgcn_update_dpp(
      __float_as_int(oldv), __float_as_int(v), CTRL, 0xF, 0xF, false));
}
template <int CTRL>
__device__ __forceinline__ int dpp_i(int v, int oldv) {
  return __builtin_amdgcn_update_dpp(oldv, v, CTRL, 0xF, 0xF, false);
}

template <int CTRL>
__device__ __forceinline__ void fps_combine2(float& val, int& idx) {
  const float tv = dpp_f<CTRL>(val, -1.0f);
  const int ti = dpp_i<CTRL>(idx, 0x7fffffff);
  const bool take = (tv > val) || (tv == val && ti < idx);
  val = take ? tv : val;
  idx = take ? ti : idx;
}

// ---------------- FPS: one block (128 thr = 2 WAVES) per batch ----------------
// Wave-count scan across rounds (8w=1477, 4w=1165..1153) shows cost rises with
// waves (barrier skew, resolve, pipeline-fill). This round probes BELOW 4:
// 2 waves x 32 pts/thread. Same LDS-instr total (64 b128/step) but 2-candidate
// resolve, half the barrier participants, VALU on 2 separate SIMDs.
// Bit-exact vs numpy: contract(off) distances, same op order, first-index
// argmax tie-break (ascending index scan; min-idx combine).
__global__ __launch_bounds__(128, 1) void fps_kernel(
    const float* __restrict__ xyz, float* __restrict__ newxyz) {
  const int b = blockIdx.x;
  const int t = threadIdx.x;
  __shared__ float4 sp[N_];      // 64 KB coords (x,y,z,0)
  __shared__ float2 rec[2][2];   // [parity][wave] = (val, idxbits)
  const float* xb = xyz + (size_t)b * N_ * 3;
  for (int p = t; p < N_; p += 128) {
    sp[p] = make_float4(xb[p * 3 + 0], xb[p * 3 + 1], xb[p * 3 + 2], 0.0f);
  }
  float dist[32];
#pragma unroll
  for (int j = 0; j < 32; ++j) dist[j] = 1e10f;
  __syncthreads();
  float4 c0 = sp[0];
  float cx = c0.x, cy = c0.y, cz = c0.z;  // farthest init = point 0
  for (int s = 0; s < S_; ++s) {
    if (t == 0) {
      float* o = newxyz + ((size_t)b * S_ + s) * 3;
      o[0] = cx; o[1] = cy; o[2] = cz;
    }
    // independent loads + distance computes (batch-issued)
    float dd[32];
#pragma unroll
    for (int j = 0; j < 32; ++j) {
      const float4 p = sp[j * 128 + t];
      dd[j] = sqdist3(p.x, p.y, p.z, cx, cy, cz);
    }
    __builtin_amdgcn_sched_barrier(0);
    // register-only min + local argmax (ascending j -> first on tie)
    float best = -1.0f;
    int bi = 0;
#pragma unroll
    for (int j = 0; j < 32; ++j) {
      const float nd = fminf(dist[j], dd[j]);
      dist[j] = nd;
      const bool take = nd > best;
      best = take ? nd : best;
      bi = take ? (j * 128 + t) : bi;
    }
    // DPP wave argmax (result complete in lane 63)
    fps_combine2<0x111>(best, bi);
    fps_combine2<0x112>(best, bi);
    fps_combine2<0x114>(best, bi);
    fps_combine2<0x118>(best, bi);
    fps_combine2<0x142>(best, bi);
    fps_combine2<0x143>(best, bi);
    const float wv = __int_as_float(__builtin_amdgcn_readlane(__float_as_int(best), 63));
    const int wi = __builtin_amdgcn_readlane(bi, 63);
    const int par = s & 1;
    if ((t & 63) == 0) {
      rec[par][t >> 6] = make_float2(wv, __int_as_float(wi));
    }
    __syncthreads();
    // resolve the 2 wave candidates redundantly (broadcast b64 reads)
    float2 r0 = rec[par][0];
    float2 r1 = rec[par][1];
    float bv = r0.x;
    int bj = __float_as_int(r0.y);
    const int i1 = __float_as_int(r1.y);
    const bool take = (r1.x > bv) || (r1.x == bv && i1 < bj);
    bv = take ? r1.x : bv;
    bj = take ? i1 : bj;
    const float4 c = sp[bj];  // broadcast read
    cx = c.x; cy = c.y; cz = c.z;
  }
}

// ---------------- KNN: 16 queries/block (4 per wave, sequential) ----------------
// One 48KB xyz stage serves 16 queries (was 4) -> staging traffic /4.
__global__ __launch_bounds__(256, 2) void knn_kernel(
    const float* __restrict__ xyz, const float* __restrict__ newxyz,
    int* __restrict__ knn_idx) {
  const int base = blockIdx.x * 16;  // 1024 queries/batch, 64 blocks/batch
  const int b = base >> 10;
  const int t = threadIdx.x;
  const int wave = t >> 6;
  const int lane = t & 63;
  __shared__ float sxx[N_];
  __shared__ float sxy[N_];
  __shared__ float sxz[N_];
  const float* xb = xyz + (size_t)b * N_ * 3;
  for (int p = t; p < N_; p += 256) {
    sxx[p] = xb[p * 3 + 0];
    sxy[p] = xb[p * 3 + 1];
    sxz[p] = xb[p * 3 + 2];
  }
  __syncthreads();
  for (int qq = 0; qq < 4; ++qq) {
    const int bs = base + wave * 4 + qq;
    const float cx = newxyz[(size_t)bs * 3 + 0];
    const float cy = newxyz[(size_t)bs * 3 + 1];
    const float cz = newxyz[(size_t)bs * 3 + 2];
    float c2;
    {
#pragma clang fp contract(off)
      float s = cx * cx;
      s = s + cy * cy;
      s = s + cz * cz;
      c2 = s;
    }
    float d[64];
    float gval[8];
    int gidx[8];
#pragma unroll
    for (int g = 0; g < 8; ++g) {
      float gv = FLT_MAX;
      int gi = g * 8;
#pragma unroll
      for (int q = 0; q < 8; ++q) {
        const int j = g * 8 + q;
        const int p = j * 64 + lane;
        const float dd = knn_dist(c2, cx, cy, cz, sxx[p], sxy[p], sxz[p]);
        d[j] = dd;
        if (dd < gv) { gv = dd; gi = j; }
      }
      gval[g] = gv; gidx[g] = gi;
    }
    int* krow = knn_idx + (size_t)bs * K_;
    for (int it = 0; it < K_; ++it) {
      float best = gval[0];
      int bj = gidx[0];
#pragma unroll
      for (int g = 1; g < 8; ++g) {
        if (gval[g] < best || (gval[g] == best && gidx[g] < bj)) { best = gval[g]; bj = gidx[g]; }
      }
      int bidx = bj * 64 + lane;
#pragma unroll
      for (int off = 32; off >= 1; off >>= 1) {
        const float ov = __shfl_xor(best, off);
        const int oi = __shfl_xor(bidx, off);
        if (ov < best || (ov == best && oi < bidx)) { best = ov; bidx = oi; }
      }
      if (lane == 0) krow[it] = bidx;
      if (lane == (bidx & 63)) {
        const int jl = bidx >> 6;
        const int gg = jl >> 3;
        const int qq2 = jl & 7;
#pragma unroll
        for (int g = 0; g < 8; ++g) {
          if (g == gg) {
#pragma unroll
            for (int q = 0; q < 8; ++q) {
              d[g * 8 + q] = (q == qq2) ? FLT_MAX : d[g * 8 + q];
            }
            float gv = FLT_MAX;
            int gi = g * 8;
#pragma unroll
            for (int q = 0; q < 8; ++q) {
              const int j = g * 8 + q;
              if (d[j] < gv) { gv = d[j]; gi = j; }
            }
            gval[g] = gv; gidx[g] = gi;
          }
        }
      }
    }
  }
}

// ---------------- MLP pass building blocks (round-7 proven) ----------------

__device__ __forceinline__ void loadw(float* __restrict__ wbuf,
                                      const float* __restrict__ w, int n, int t) {
  for (int i = t; i < n; i += 256) wbuf[i] = w[i];
}

__device__ __forceinline__ void loadw_half(float* __restrict__ wbuf,
                                           const float* __restrict__ w2, int ofs, int t) {
  for (int i = t; i < 64 * 64; i += 256) {
    const int c = i >> 6, j = i & 63;
    wbuf[i] = w2[c * 128 + ofs + j];
  }
}

__device__ __forceinline__ void build_x0(float* __restrict__ act,
    const float* __restrict__ xyz, const float* __restrict__ points,
    const int* __restrict__ knn_idx, const float* __restrict__ newxyz,
    int bs, int t) {
  const int b = bs >> 10;
  const int* krow = knn_idx + (size_t)bs * K_;
  const float cx = newxyz[(size_t)bs * 3 + 0];
  const float cy = newxyz[(size_t)bs * 3 + 1];
  const float cz = newxyz[(size_t)bs * 3 + 2];
  for (int i = t; i < K_ * CIN0; i += 256) {
    const int k = i / CIN0;
    const int c = i - k * CIN0;
    const int p = krow[k];
    float v;
    if (c < 3) {
      v = xyz[((size_t)b * N_ + p) * 3 + c] - (c == 0 ? cx : (c == 1 ? cy : cz));
    } else {
      v = points[((size_t)b * N_ + p) * 64 + (c - 3)];
    }
    act[k * AST + c] = v;
  }
}

template <int CIN>
__device__ __forceinline__ void matmul64(const float* __restrict__ act,
    const float* __restrict__ wbuf, const float* __restrict__ bias,
    float* __restrict__ out, int t) {
  const int k = t >> 3;
  const int g = t & 7;
  float acc[8];
#pragma unroll
  for (int j = 0; j < 8; ++j) acc[j] = bias[g * 8 + j];
  for (int c = 0; c < CIN; ++c) {
    const float xv = act[k * AST + c];
#pragma unroll
    for (int j = 0; j < 8; ++j) acc[j] += xv * wbuf[c * 64 + g * 8 + j];
  }
#pragma unroll
  for (int j = 0; j < 8; ++j) out[k * AST + g * 8 + j] = acc[j];
}

__device__ __forceinline__ void norm_relu64(float* __restrict__ act,
    const float* __restrict__ scale, const float* __restrict__ shift, int t) {
  for (int i = t; i < K_ * 64; i += 256) {
    const int k = i >> 6, c = i & 63;
    const float v = act[k * AST + c] * scale[c] + shift[c];
    act[k * AST + c] = fmaxf(v, 0.0f);
  }
}

__device__ __forceinline__ void stats64(const float* __restrict__ out,
    float* __restrict__ psum, float* __restrict__ psq, int bs, int ofs, int t) {
  if (t < 64) {
    float s = 0.f, q = 0.f;
    for (int k = 0; k < K_; ++k) {
      const float v = out[k * AST + t];
      s += v; q += v * v;
    }
    psum[(size_t)bs * 128 + ofs + t] = s;
    psq[(size_t)bs * 128 + ofs + t] = q;
  }
}

__device__ __forceinline__ void minmax64(const float* __restrict__ out,
    float* __restrict__ maxraw, float* __restrict__ minbuf, int bs, int ofs, int t) {
  if (t >= 64 && t < 128) {
    const int ch = t - 64;
    float mx = -FLT_MAX, mn = FLT_MAX;
    for (int k = 0; k < K_; ++k) {
      const float v = out[k * AST + ch];
      mx = fmaxf(mx, v); mn = fminf(mn, v);
    }
    maxraw[(size_t)bs * 128 + ofs + ch] = mx;
    minbuf[(size_t)bs * 128 + ofs + ch] = mn;
  }
}

// ======== FAST PATH (activations stored in ws) ========

__global__ __launch_bounds__(256) void passA_store_kernel(
    const float* __restrict__ xyz, const float* __restrict__ points,
    const float* __restrict__ newxyz, const int* __restrict__ knn_idx,
    const float* __restrict__ w0, const float* __restrict__ b0,
    float* __restrict__ psum, float* __restrict__ psq, float* __restrict__ zbuf) {
  __shared__ float actA[K_ * AST];
  __shared__ float outB[K_ * AST];
  __shared__ float wbuf[CIN0 * 64];
  const int bs = blockIdx.x, t = threadIdx.x;
  build_x0(actA, xyz, points, knn_idx, newxyz, bs, t);
  loadw(wbuf, w0, CIN0 * 64, t);
  __syncthreads();
  matmul64<CIN0>(actA, wbuf, b0, outB, t);
  __syncthreads();
  stats64(outB, psum, psq, bs, 0, t);
  float* zrow = zbuf + (size_t)bs * 2048;
  for (int i = t; i < 2048; i += 256) zrow[i] = outB[(i >> 6) * AST + (i & 63)];
}

__global__ __launch_bounds__(256) void passB_z_kernel(
    const float* __restrict__ w1, const float* __restrict__ b1,
    const float* __restrict__ scales, const float* __restrict__ shifts,
    float* __restrict__ psum, float* __restrict__ psq, float* __restrict__ zbuf) {
  __shared__ float actA[K_ * AST];
  __shared__ float outB[K_ * AST];
  __shared__ float wbuf[64 * 64];
  const int bs = blockIdx.x, t = threadIdx.x;
  float* zrow = zbuf + (size_t)bs * 2048;
  for (int i = t; i < 2048; i += 256) outB[(i >> 6) * AST + (i & 63)] = zrow[i];
  loadw(wbuf, w1, 64 * 64, t);
  __syncthreads();
  norm_relu64(outB, scales, shifts, t);
  __syncthreads();
  matmul64<64>(outB, wbuf, b1, actA, t);
  __syncthreads();
  stats64(actA, psum, psq, bs, 0, t);
  for (int i = t; i < 2048; i += 256) zrow[i] = actA[(i >> 6) * AST + (i & 63)];
}

__global__ __launch_bounds__(256) void passC_z_kernel(
    const float* __restrict__ w2, const float* __restrict__ b2,
    const float* __restrict__ scales1, const float* __restrict__ shifts1,
    float* __restrict__ psum, float* __restrict__ psq,
    float* __restrict__ maxraw, float* __restrict__ minbuf,
    const float* __restrict__ zbuf) {
  __shared__ float actA[K_ * AST];
  __shared__ float outB[K_ * AST];
  __shared__ float wbuf[64 * 64];
  const int bs = blockIdx.x, t = threadIdx.x;
  const float* zrow = zbuf + (size_t)bs * 2048;
  for (int i = t; i < 2048; i += 256) actA[(i >> 6) * AST + (i & 63)] = zrow[i];
  loadw_half(wbuf, w2, 0, t);
  __syncthreads();
  norm_relu64(actA, scales1, shifts1, t);
  __syncthreads();
  matmul64<64>(actA, wbuf, b2, outB, t);
  __syncthreads();
  stats64(outB, psum, psq, bs, 0, t);
  minmax64(outB, maxraw, minbuf, bs, 0, t);
  loadw_half(wbuf, w2, 64, t);
  __syncthreads();
  matmul64<64>(actA, wbuf, b2 + 64, outB, t);
  __syncthreads();
  stats64(outB, psum, psq, bs, 64, t);
  minmax64(outB, maxraw, minbuf, bs, 64, t);
}

// ======== FALLBACK PATH (recompute) ========

__global__ __launch_bounds__(256) void passA_kernel(
    const float* __restrict__ xyz, const float* __restrict__ points,
    const float* __restrict__ newxyz, const int* __restrict__ knn_idx,
    const float* __restrict__ w0, const float* __restrict__ b0,
    float* __restrict__ psum, float* __restrict__ psq) {
  __shared__ float actA[K_ * AST];
  __shared__ float outB[K_ * AST];
  __shared__ float wbuf[CIN0 * 64];
  const int bs = blockIdx.x, t = threadIdx.x;
  build_x0(actA, xyz, points, knn_idx, newxyz, bs, t);
  loadw(wbuf, w0, CIN0 * 64, t);
  __syncthreads();
  matmul64<CIN0>(actA, wbuf, b0, outB, t);
  __syncthreads();
  stats64(outB, psum, psq, bs, 0, t);
}

__global__ __launch_bounds__(256) void passB_kernel(
    const float* __restrict__ xyz, const float* __restrict__ points,
    const float* __restrict__ newxyz, const int* __restrict__ knn_idx,
    const float* __restrict__ w0, const float* __restrict__ b0,
    const float* __restrict__ w1, const float* __restrict__ b1,
    const float* __restrict__ scales, const float* __restrict__ shifts,
    float* __restrict__ psum, float* __restrict__ psq) {
  __shared__ float actA[K_ * AST];
  __shared__ float outB[K_ * AST];
  __shared__ float wbuf[CIN0 * 64];
  const int bs = blockIdx.x, t = threadIdx.x;
  build_x0(actA, xyz, points, knn_idx, newxyz, bs, t);
  loadw(wbuf, w0, CIN0 * 64, t);
  __syncthreads();
  matmul64<CIN0>(actA, wbuf, b0, outB, t);
  __syncthreads();
  norm_relu64(outB, scales, shifts, t);
  loadw(wbuf, w1, 64 * 64, t);
  __syncthreads();
  matmul64<64>(outB, wbuf, b1, actA, t);
  __syncthreads();
  stats64(actA, psum, psq, bs, 0, t);
}

__global__ __launch_bounds__(256) void passC_kernel(
    const float* __restrict__ xyz, const float* __restrict__ points,
    const float* __restrict__ newxyz, const int* __restrict__ knn_idx,
    const float* __restrict__ w0, const float* __restrict__ b0,
    const float* __restrict__ w1, const float* __restrict__ b1,
    const float* __restrict__ w2, const float* __restrict__ b2,
    const float* __restrict__ scales, const float* __restrict__ shifts,
    float* __restrict__ psum, float* __restrict__ psq,
    float* __restrict__ maxraw, float* __restrict__ minbuf) {
  __shared__ float actA[K_ * AST];
  __shared__ float outB[K_ * AST];
  __shared__ float wbuf[CIN0 * 64];
  const int bs = blockIdx.x, t = threadIdx.x;
  build_x0(actA, xyz, points, knn_idx, newxyz, bs, t);
  loadw(wbuf, w0, CIN0 * 64, t);
  __syncthreads();
  matmul64<CIN0>(actA, wbuf, b0, outB, t);
  __syncthreads();
  norm_relu64(outB, scales, shifts, t);
  loadw(wbuf, w1, 64 * 64, t);
  __syncthreads();
  matmul64<64>(outB, wbuf, b1, actA, t);
  __syncthreads();
  norm_relu64(actA, scales + 128, shifts + 128, t);
  loadw_half(wbuf, w2, 0, t);
  __syncthreads();
  matmul64<64>(actA, wbuf, b2, outB, t);
  __syncthreads();
  stats64(outB, psum, psq, bs, 0, t);
  minmax64(outB, maxraw, minbuf, bs, 0, t);
  loadw_half(wbuf, w2, 64, t);
  __syncthreads();
  matmul64<64>(actA, wbuf, b2 + 64, outB, t);
  __syncthreads();
  stats64(outB, psum, psq, bs, 64, t);
  minmax64(outB, maxraw, minbuf, bs, 64, t);
}

// ---------------- BN finalize ----------------
__global__ __launch_bounds__(256) void finalize_kernel(
    const float* __restrict__ psum, const float* __restrict__ psq,
    const float* __restrict__ g, const float* __restrict__ be,
    float* __restrict__ scale, float* __restrict__ shift) {
  const int ch = blockIdx.x, t = threadIdx.x;
  __shared__ float ss[256];
  __shared__ float sq[256];
  float s = 0.f, q = 0.f;
  for (int p = t; p < NBS; p += 256) {
    s += psum[(size_t)p * 128 + ch];
    q += psq[(size_t)p * 128 + ch];
  }
  ss[t] = s; sq[t] = q;
  __syncthreads();
  for (int off = 128; off >= 1; off >>= 1) {
    if (t < off) { ss[t] += ss[t + off]; sq[t] += sq[t + off]; }
    __syncthreads();
  }
  if (t == 0) {
    const float invN = 1.0f / (float)(B_ * S_ * K_);
    const float mean = ss[0] * invN;
    const float var = sq[0] * invN - mean * mean;
    const float sc = g[ch] / sqrtf(var + 1e-5f);
    scale[ch] = sc;
    shift[ch] = be[ch] - mean * sc;
  }
}

// ---------------- Final ----------------
__global__ __launch_bounds__(256) void final_kernel(
    const float* __restrict__ minbuf, const float* __restrict__ scale,
    const float* __restrict__ shift, float* __restrict__ out) {
  const int i = blockIdx.x * 256 + threadIdx.x;  // < B*S*128
  const int ch = i & 127;
  const float sc = scale[ch], sh = shift[ch];
  const float mx = out[NEWXYZ_FLOATS + i];
  const float mn = minbuf[i];
  const float v = sc * (sc >= 0.f ? mx : mn) + sh;
  out[NEWXYZ_FLOATS + i] = fmaxf(v, 0.f);
}

// ---------------- host ----------------
extern "C" void kernel_launch(void* const* d_in, const int* in_sizes, int n_in,
                              void* d_out, int out_size, void* d_ws, size_t ws_size,
                              hipStream_t stream) {
  const float* xyz = (const float*)d_in[0];
  const float* points = (const float*)d_in[1];
  const float* w0 = (const float*)d_in[2];
  const float* b0 = (const float*)d_in[3];
  const float* g0 = (const float*)d_in[4];
  const float* be0 = (const float*)d_in[5];
  const float* w1 = (const float*)d_in[6];
  const float* b1 = (const float*)d_in[7];
  const float* g1 = (const float*)d_in[8];
  const float* be1 = (const float*)d_in[9];
  const float* w2 = (const float*)d_in[10];
  const float* b2 = (const float*)d_in[11];
  const float* g2 = (const float*)d_in[12];
  const float* be2 = (const float*)d_in[13];
  float* out = (float*)d_out;
  float* newxyz = out;
  float* maxraw = out + NEWXYZ_FLOATS;

  float* ws = (float*)d_ws;
  const size_t NEED_FAST =
      (size_t)(524288 + 16384 * 2048 + 2 * NBS * 128 + 768 + NBS * 128) * 4;

  fps_kernel<<<B_, 128, 0, stream>>>(xyz, newxyz);

  if (ws_size >= NEED_FAST) {
    int* knn_idx = (int*)ws;
    float* zbuf = ws + 524288;
    float* psum = zbuf + (size_t)16384 * 2048;
    float* psq = psum + (size_t)NBS * 128;
    float* scales = psq + (size_t)NBS * 128;
    float* shifts = scales + 384;
    float* minbuf = shifts + 384;
    knn_kernel<<<NBS / 16, 256, 0, stream>>>(xyz, newxyz, knn_idx);
    passA_store_kernel<<<NBS, 256, 0, stream>>>(xyz, points, newxyz, knn_idx, w0, b0,
                                                psum, psq, zbuf);
    finalize_kernel<<<64, 256, 0, stream>>>(psum, psq, g0, be0, scales, shifts);
    passB_z_kernel<<<NBS, 256, 0, stream>>>(w1, b1, scales, shifts, psum, psq, zbuf);
    finalize_kernel<<<64, 256, 0, stream>>>(psum, psq, g1, be1, scales + 128, shifts + 128);
    passC_z_kernel<<<NBS, 256, 0, stream>>>(w2, b2, scales + 128, shifts + 128,
                                            psum, psq, maxraw, minbuf, zbuf);
    finalize_kernel<<<128, 256, 0, stream>>>(psum, psq, g2, be2, scales + 256, shifts + 256);
    final_kernel<<<(B_ * S_ * 128) / 256, 256, 0, stream>>>(minbuf, scales + 256,
                                                            shifts + 256, out);
  } else {
    int* knn_idx = (int*)ws;
    float* psum = ws + 524288;
    float* psq = psum + (size_t)NBS * 128;
    float* scales = psq + (size_t)NBS * 128;
    float* shifts = scales + 384;
    float* minbuf = shifts + 384;
    knn_kernel<<<NBS / 16, 256, 0, stream>>>(xyz, newxyz, knn_idx);
    passA_kernel<<<NBS, 256, 0, stream>>>(xyz, points, newxyz, knn_idx, w0, b0, psum, psq);
    finalize_kernel<<<64, 256, 0, stream>>>(psum, psq, g0, be0, scales, shifts);
    passB_kernel<<<NBS, 256, 0, stream>>>(xyz, points, newxyz, knn_idx, w0, b0, w1, b1,
                                          scales, shifts, psum, psq);
    finalize_kernel<<<64, 256, 0, stream>>>(psum, psq, g1, be1, scales + 128, shifts + 128);
    passC_kernel<<<NBS, 256, 0, stream>>>(xyz, points, newxyz, knn_idx, w0, b0, w1, b1, w2, b2,
                                          scales, shifts, psum, psq, maxraw, minbuf);
    finalize_kernel<<<128, 256, 0, stream>>>(psum, psq, g2, be2, scales + 256, shifts + 256);
    final_kernel<<<(B_ * S_ * 128) / 256, 256, 0, stream>>>(minbuf, scales + 256,
                                                            shifts + 256, out);
  }
}

// Round 11
// 2034.953 us; speedup vs baseline: 1.9580x; 1.3249x over previous
//
#include <hip/hip_runtime.h>
#include <float.h>
#include <math.h>

// Problem constants
#define B_ 16
#define N_ 4096
#define S_ 1024
#define K_ 32
#define CIN0 67              // 3 + 64
#define NBS (B_ * S_)        // 16384
#define NEWXYZ_FLOATS (B_ * S_ * 3)  // 49152
#define AST 68               // LDS activation row stride

// ---------------- helpers ----------------

__device__ __forceinline__ float sqdist3(float x, float y, float z,
                                         float cx, float cy, float cz) {
#pragma clang fp contract(off)
  float dx = x - cx, dy = y - cy, dz = z - cz;
  float s = dx * dx;
  s = s + dy * dy;
  s = s + dz * dz;
  return s;
}

__device__ __forceinline__ float knn_dist(float c2, float cx, float cy, float cz,
                                          float x, float y, float z) {
#pragma clang fp contract(off)
  float dot = cx * x; dot = dot + cy * y; dot = dot + cz * z;
  float x2 = x * x;   x2 = x2 + y * y;   x2 = x2 + z * z;
  float d = c2 - 2.0f * dot;
  d = d + x2;
  return d;
}

// ---- DPP cross-lane (gfx9: row_shr:N=0x110|N, row_bcast15=0x142, row_bcast31=0x143) ----
template <int CTRL>
__device__ __forceinline__ float dpp_f(float v, float oldv) {
  return __int_as_float(__builtin_amdgcn_update_dpp(
      __float_as_int(oldv), __float_as_int(v), CTRL, 0xF, 0xF, false));
}
template <int CTRL>
__device__ __forceinline__ int dpp_i(int v, int oldv) {
  return __builtin_amdgcn_update_dpp(oldv, v, CTRL, 0xF, 0xF, false);
}

template <int CTRL>
__device__ __forceinline__ void fps_combine2(float& val, int& idx) {
  const float tv = dpp_f<CTRL>(val, -1.0f);
  const int ti = dpp_i<CTRL>(idx, 0x7fffffff);
  const bool take = (tv > val) || (tv == val && ti < idx);
  val = take ? tv : val;
  idx = take ? ti : idx;
}

// ---------------- FPS: one block (256 thr = 4 waves) per batch ----------------
// Rounds 2-10 lesson: coord access dominates (~2100 of 2700 cyc/step) because
// the allocator refuses to keep 48 coord VGPRs live (remat from global r3,
// scratch r4/5, LDS r6/7; wave-scan: 4 waves optimal). Fix: park coords in
// AGPRs (unified file, untouched by the allocator at our VGPR pressure) via
// the "a"-constraint v_accvgpr_write/read idiom. Volatile asm: never hoisted
// to VGPRs, never rematerialized. Coord fetch becomes 48 VALU-rate reads on
// the wave's own SIMD: no LDS pipe sharing, no memory latency.
// Bit-exact vs numpy: contract(off) distances, same op order, first-index
// argmax tie-break (thread owns consecutive points t*16+j, ascending scan).
__global__ __launch_bounds__(256, 1) void fps_kernel(
    const float* __restrict__ xyz, float* __restrict__ newxyz) {
  const int b = blockIdx.x;
  const int t = threadIdx.x;
  __shared__ float4 sp[N_];      // 64 KB coords, only for the per-step broadcast fetch
  __shared__ float2 rec[2][4];   // [parity][wave] = (val, idxbits)
  const float* xb = xyz + (size_t)b * N_ * 3;
  for (int p = t; p < N_; p += 256) {
    sp[p] = make_float4(xb[p * 3 + 0], xb[p * 3 + 1], xb[p * 3 + 2], 0.0f);
  }
  // park this thread's 16 consecutive points in AGPRs
  float ax[16], ay[16], az[16];
#pragma unroll
  for (int j = 0; j < 16; ++j) {
    const int p = t * 16 + j;
    const float x = xb[p * 3 + 0];
    const float y = xb[p * 3 + 1];
    const float z = xb[p * 3 + 2];
    asm volatile("v_accvgpr_write_b32 %0, %1" : "=a"(ax[j]) : "v"(x));
    asm volatile("v_accvgpr_write_b32 %0, %1" : "=a"(ay[j]) : "v"(y));
    asm volatile("v_accvgpr_write_b32 %0, %1" : "=a"(az[j]) : "v"(z));
  }
  float dist[16];
#pragma unroll
  for (int j = 0; j < 16; ++j) dist[j] = 1e10f;
  __syncthreads();
  float cx = xb[0], cy = xb[1], cz = xb[2];  // farthest init = point 0
  for (int s = 0; s < S_; ++s) {
    if (t == 0) {
      float* o = newxyz + ((size_t)b * S_ + s) * 3;
      o[0] = cx; o[1] = cy; o[2] = cz;
    }
    // coord fetch from AGPRs (VALU-rate, per-SIMD) + independent distances
    float dd[16];
#pragma unroll
    for (int j = 0; j < 16; ++j) {
      float x, y, z;
      asm volatile("v_accvgpr_read_b32 %0, %1" : "=v"(x) : "a"(ax[j]));
      asm volatile("v_accvgpr_read_b32 %0, %1" : "=v"(y) : "a"(ay[j]));
      asm volatile("v_accvgpr_read_b32 %0, %1" : "=v"(z) : "a"(az[j]));
      dd[j] = sqdist3(x, y, z, cx, cy, cz);
    }
    __builtin_amdgcn_sched_barrier(0);
    // register-only min + local argmax (ascending global idx -> first on tie)
    float best = -1.0f;
    int bi = 0;
#pragma unroll
    for (int j = 0; j < 16; ++j) {
      const float nd = fminf(dist[j], dd[j]);
      dist[j] = nd;
      const bool take = nd > best;
      best = take ? nd : best;
      bi = take ? (t * 16 + j) : bi;
    }
    // DPP wave argmax (result complete in lane 63)
    fps_combine2<0x111>(best, bi);
    fps_combine2<0x112>(best, bi);
    fps_combine2<0x114>(best, bi);
    fps_combine2<0x118>(best, bi);
    fps_combine2<0x142>(best, bi);
    fps_combine2<0x143>(best, bi);
    const float wv = __int_as_float(__builtin_amdgcn_readlane(__float_as_int(best), 63));
    const int wi = __builtin_amdgcn_readlane(bi, 63);
    const int par = s & 1;
    if ((t & 63) == 0) {
      rec[par][t >> 6] = make_float2(wv, __int_as_float(wi));
    }
    __syncthreads();
    // resolve the 4 wave candidates redundantly (broadcast b64 reads)
    float2 r0 = rec[par][0];
    float bv = r0.x;
    int bj = __float_as_int(r0.y);
#pragma unroll
    for (int w = 1; w < 4; ++w) {
      const float2 r = rec[par][w];
      const int iw = __float_as_int(r.y);
      const bool take = (r.x > bv) || (r.x == bv && iw < bj);
      bv = take ? r.x : bv;
      bj = take ? iw : bj;
    }
    const float4 c = sp[bj];  // broadcast read
    cx = c.x; cy = c.y; cz = c.z;
  }
}

// ---------------- KNN: one wave per query, 4 queries/block (r7 proven) ----------------
__global__ __launch_bounds__(256, 2) void knn_kernel(
    const float* __restrict__ xyz, const float* __restrict__ newxyz,
    int* __restrict__ knn_idx) {
  const int bs0 = blockIdx.x * 4;
  const int b = bs0 >> 10;
  const int t = threadIdx.x;
  const int wave = t >> 6;
  const int lane = t & 63;
  __shared__ float sxx[N_];
  __shared__ float sxy[N_];
  __shared__ float sxz[N_];
  const float* xb = xyz + (size_t)b * N_ * 3;
  for (int p = t; p < N_; p += 256) {
    sxx[p] = xb[p * 3 + 0];
    sxy[p] = xb[p * 3 + 1];
    sxz[p] = xb[p * 3 + 2];
  }
  __syncthreads();
  const int bs = bs0 + wave;
  const float cx = newxyz[(size_t)bs * 3 + 0];
  const float cy = newxyz[(size_t)bs * 3 + 1];
  const float cz = newxyz[(size_t)bs * 3 + 2];
  float c2;
  {
#pragma clang fp contract(off)
    float s = cx * cx;
    s = s + cy * cy;
    s = s + cz * cz;
    c2 = s;
  }
  float d[64];
  float gval[8];
  int gidx[8];
#pragma unroll
  for (int g = 0; g < 8; ++g) {
    float gv = FLT_MAX;
    int gi = g * 8;
#pragma unroll
    for (int q = 0; q < 8; ++q) {
      const int j = g * 8 + q;
      const int p = j * 64 + lane;
      const float dd = knn_dist(c2, cx, cy, cz, sxx[p], sxy[p], sxz[p]);
      d[j] = dd;
      if (dd < gv) { gv = dd; gi = j; }
    }
    gval[g] = gv; gidx[g] = gi;
  }
  int* krow = knn_idx + (size_t)bs * K_;
  for (int it = 0; it < K_; ++it) {
    float best = gval[0];
    int bj = gidx[0];
#pragma unroll
    for (int g = 1; g < 8; ++g) {
      if (gval[g] < best || (gval[g] == best && gidx[g] < bj)) { best = gval[g]; bj = gidx[g]; }
    }
    int bidx = bj * 64 + lane;
#pragma unroll
    for (int off = 32; off >= 1; off >>= 1) {
      const float ov = __shfl_xor(best, off);
      const int oi = __shfl_xor(bidx, off);
      if (ov < best || (ov == best && oi < bidx)) { best = ov; bidx = oi; }
    }
    if (lane == 0) krow[it] = bidx;
    if (lane == (bidx & 63)) {
      const int jl = bidx >> 6;
      const int gg = jl >> 3;
      const int qq = jl & 7;
#pragma unroll
      for (int g = 0; g < 8; ++g) {
        if (g == gg) {
#pragma unroll
          for (int q = 0; q < 8; ++q) {
            d[g * 8 + q] = (q == qq) ? FLT_MAX : d[g * 8 + q];
          }
          float gv = FLT_MAX;
          int gi = g * 8;
#pragma unroll
          for (int q = 0; q < 8; ++q) {
            const int j = g * 8 + q;
            if (d[j] < gv) { gv = d[j]; gi = j; }
          }
          gval[g] = gv; gidx[g] = gi;
        }
      }
    }
  }
}

// ---------------- MLP pass building blocks (r7 proven) ----------------

__device__ __forceinline__ void loadw(float* __restrict__ wbuf,
                                      const float* __restrict__ w, int n, int t) {
  for (int i = t; i < n; i += 256) wbuf[i] = w[i];
}

__device__ __forceinline__ void loadw_half(float* __restrict__ wbuf,
                                           const float* __restrict__ w2, int ofs, int t) {
  for (int i = t; i < 64 * 64; i += 256) {
    const int c = i >> 6, j = i & 63;
    wbuf[i] = w2[c * 128 + ofs + j];
  }
}

__device__ __forceinline__ void build_x0(float* __restrict__ act,
    const float* __restrict__ xyz, const float* __restrict__ points,
    const int* __restrict__ knn_idx, const float* __restrict__ newxyz,
    int bs, int t) {
  const int b = bs >> 10;
  const int* krow = knn_idx + (size_t)bs * K_;
  const float cx = newxyz[(size_t)bs * 3 + 0];
  const float cy = newxyz[(size_t)bs * 3 + 1];
  const float cz = newxyz[(size_t)bs * 3 + 2];
  for (int i = t; i < K_ * CIN0; i += 256) {
    const int k = i / CIN0;
    const int c = i - k * CIN0;
    const int p = krow[k];
    float v;
    if (c < 3) {
      v = xyz[((size_t)b * N_ + p) * 3 + c] - (c == 0 ? cx : (c == 1 ? cy : cz));
    } else {
      v = points[((size_t)b * N_ + p) * 64 + (c - 3)];
    }
    act[k * AST + c] = v;
  }
}

template <int CIN>
__device__ __forceinline__ void matmul64(const float* __restrict__ act,
    const float* __restrict__ wbuf, const float* __restrict__ bias,
    float* __restrict__ out, int t) {
  const int k = t >> 3;
  const int g = t & 7;
  float acc[8];
#pragma unroll
  for (int j = 0; j < 8; ++j) acc[j] = bias[g * 8 + j];
  for (int c = 0; c < CIN; ++c) {
    const float xv = act[k * AST + c];
#pragma unroll
    for (int j = 0; j < 8; ++j) acc[j] += xv * wbuf[c * 64 + g * 8 + j];
  }
#pragma unroll
  for (int j = 0; j < 8; ++j) out[k * AST + g * 8 + j] = acc[j];
}

__device__ __forceinline__ void norm_relu64(float* __restrict__ act,
    const float* __restrict__ scale, const float* __restrict__ shift, int t) {
  for (int i = t; i < K_ * 64; i += 256) {
    const int k = i >> 6, c = i & 63;
    const float v = act[k * AST + c] * scale[c] + shift[c];
    act[k * AST + c] = fmaxf(v, 0.0f);
  }
}

__device__ __forceinline__ void stats64(const float* __restrict__ out,
    float* __restrict__ psum, float* __restrict__ psq, int bs, int ofs, int t) {
  if (t < 64) {
    float s = 0.f, q = 0.f;
    for (int k = 0; k < K_; ++k) {
      const float v = out[k * AST + t];
      s += v; q += v * v;
    }
    psum[(size_t)bs * 128 + ofs + t] = s;
    psq[(size_t)bs * 128 + ofs + t] = q;
  }
}

__device__ __forceinline__ void minmax64(const float* __restrict__ out,
    float* __restrict__ maxraw, float* __restrict__ minbuf, int bs, int ofs, int t) {
  if (t >= 64 && t < 128) {
    const int ch = t - 64;
    float mx = -FLT_MAX, mn = FLT_MAX;
    for (int k = 0; k < K_; ++k) {
      const float v = out[k * AST + ch];
      mx = fmaxf(mx, v); mn = fminf(mn, v);
    }
    maxraw[(size_t)bs * 128 + ofs + ch] = mx;
    minbuf[(size_t)bs * 128 + ofs + ch] = mn;
  }
}

// ======== FAST PATH (activations stored in ws) ========

__global__ __launch_bounds__(256) void passA_store_kernel(
    const float* __restrict__ xyz, const float* __restrict__ points,
    const float* __restrict__ newxyz, const int* __restrict__ knn_idx,
    const float* __restrict__ w0, const float* __restrict__ b0,
    float* __restrict__ psum, float* __restrict__ psq, float* __restrict__ zbuf) {
  __shared__ float actA[K_ * AST];
  __shared__ float outB[K_ * AST];
  __shared__ float wbuf[CIN0 * 64];
  const int bs = blockIdx.x, t = threadIdx.x;
  build_x0(actA, xyz, points, knn_idx, newxyz, bs, t);
  loadw(wbuf, w0, CIN0 * 64, t);
  __syncthreads();
  matmul64<CIN0>(actA, wbuf, b0, outB, t);
  __syncthreads();
  stats64(outB, psum, psq, bs, 0, t);
  float* zrow = zbuf + (size_t)bs * 2048;
  for (int i = t; i < 2048; i += 256) zrow[i] = outB[(i >> 6) * AST + (i & 63)];
}

__global__ __launch_bounds__(256) void passB_z_kernel(
    const float* __restrict__ w1, const float* __restrict__ b1,
    const float* __restrict__ scales, const float* __restrict__ shifts,
    float* __restrict__ psum, float* __restrict__ psq, float* __restrict__ zbuf) {
  __shared__ float actA[K_ * AST];
  __shared__ float outB[K_ * AST];
  __shared__ float wbuf[64 * 64];
  const int bs = blockIdx.x, t = threadIdx.x;
  float* zrow = zbuf + (size_t)bs * 2048;
  for (int i = t; i < 2048; i += 256) outB[(i >> 6) * AST + (i & 63)] = zrow[i];
  loadw(wbuf, w1, 64 * 64, t);
  __syncthreads();
  norm_relu64(outB, scales, shifts, t);
  __syncthreads();
  matmul64<64>(outB, wbuf, b1, actA, t);
  __syncthreads();
  stats64(actA, psum, psq, bs, 0, t);
  for (int i = t; i < 2048; i += 256) zrow[i] = actA[(i >> 6) * AST + (i & 63)];
}

__global__ __launch_bounds__(256) void passC_z_kernel(
    const float* __restrict__ w2, const float* __restrict__ b2,
    const float* __restrict__ scales1, const float* __restrict__ shifts1,
    float* __restrict__ psum, float* __restrict__ psq,
    float* __restrict__ maxraw, float* __restrict__ minbuf,
    const float* __restrict__ zbuf) {
  __shared__ float actA[K_ * AST];
  __shared__ float outB[K_ * AST];
  __shared__ float wbuf[64 * 64];
  const int bs = blockIdx.x, t = threadIdx.x;
  const float* zrow = zbuf + (size_t)bs * 2048;
  for (int i = t; i < 2048; i += 256) actA[(i >> 6) * AST + (i & 63)] = zrow[i];
  loadw_half(wbuf, w2, 0, t);
  __syncthreads();
  norm_relu64(actA, scales1, shifts1, t);
  __syncthreads();
  matmul64<64>(actA, wbuf, b2, outB, t);
  __syncthreads();
  stats64(outB, psum, psq, bs, 0, t);
  minmax64(outB, maxraw, minbuf, bs, 0, t);
  loadw_half(wbuf, w2, 64, t);
  __syncthreads();
  matmul64<64>(actA, wbuf, b2 + 64, outB, t);
  __syncthreads();
  stats64(outB, psum, psq, bs, 64, t);
  minmax64(outB, maxraw, minbuf, bs, 64, t);
}

// ======== FALLBACK PATH (recompute) ========

__global__ __launch_bounds__(256) void passA_kernel(
    const float* __restrict__ xyz, const float* __restrict__ points,
    const float* __restrict__ newxyz, const int* __restrict__ knn_idx,
    const float* __restrict__ w0, const float* __restrict__ b0,
    float* __restrict__ psum, float* __restrict__ psq) {
  __shared__ float actA[K_ * AST];
  __shared__ float outB[K_ * AST];
  __shared__ float wbuf[CIN0 * 64];
  const int bs = blockIdx.x, t = threadIdx.x;
  build_x0(actA, xyz, points, knn_idx, newxyz, bs, t);
  loadw(wbuf, w0, CIN0 * 64, t);
  __syncthreads();
  matmul64<CIN0>(actA, wbuf, b0, outB, t);
  __syncthreads();
  stats64(outB, psum, psq, bs, 0, t);
}

__global__ __launch_bounds__(256) void passB_kernel(
    const float* __restrict__ xyz, const float* __restrict__ points,
    const float* __restrict__ newxyz, const int* __restrict__ knn_idx,
    const float* __restrict__ w0, const float* __restrict__ b0,
    const float* __restrict__ w1, const float* __restrict__ b1,
    const float* __restrict__ scales, const float* __restrict__ shifts,
    float* __restrict__ psum, float* __restrict__ psq) {
  __shared__ float actA[K_ * AST];
  __shared__ float outB[K_ * AST];
  __shared__ float wbuf[CIN0 * 64];
  const int bs = blockIdx.x, t = threadIdx.x;
  build_x0(actA, xyz, points, knn_idx, newxyz, bs, t);
  loadw(wbuf, w0, CIN0 * 64, t);
  __syncthreads();
  matmul64<CIN0>(actA, wbuf, b0, outB, t);
  __syncthreads();
  norm_relu64(outB, scales, shifts, t);
  loadw(wbuf, w1, 64 * 64, t);
  __syncthreads();
  matmul64<64>(outB, wbuf, b1, actA, t);
  __syncthreads();
  stats64(actA, psum, psq, bs, 0, t);
}

__global__ __launch_bounds__(256) void passC_kernel(
    const float* __restrict__ xyz, const float* __restrict__ points,
    const float* __restrict__ newxyz, const int* __restrict__ knn_idx,
    const float* __restrict__ w0, const float* __restrict__ b0,
    const float* __restrict__ w1, const float* __restrict__ b1,
    const float* __restrict__ w2, const float* __restrict__ b2,
    const float* __restrict__ scales, const float* __restrict__ shifts,
    float* __restrict__ psum, float* __restrict__ psq,
    float* __restrict__ maxraw, float* __restrict__ minbuf) {
  __shared__ float actA[K_ * AST];
  __shared__ float outB[K_ * AST];
  __shared__ float wbuf[CIN0 * 64];
  const int bs = blockIdx.x, t = threadIdx.x;
  build_x0(actA, xyz, points, knn_idx, newxyz, bs, t);
  loadw(wbuf, w0, CIN0 * 64, t);
  __syncthreads();
  matmul64<CIN0>(actA, wbuf, b0, outB, t);
  __syncthreads();
  norm_relu64(outB, scales, shifts, t);
  loadw(wbuf, w1, 64 * 64, t);
  __syncthreads();
  matmul64<64>(outB, wbuf, b1, actA, t);
  __syncthreads();
  norm_relu64(actA, scales + 128, shifts + 128, t);
  loadw_half(wbuf, w2, 0, t);
  __syncthreads();
  matmul64<64>(actA, wbuf, b2, outB, t);
  __syncthreads();
  stats64(outB, psum, psq, bs, 0, t);
  minmax64(outB, maxraw, minbuf, bs, 0, t);
  loadw_half(wbuf, w2, 64, t);
  __syncthreads();
  matmul64<64>(actA, wbuf, b2 + 64, outB, t);
  __syncthreads();
  stats64(outB, psum, psq, bs, 64, t);
  minmax64(outB, maxraw, minbuf, bs, 64, t);
}

// ---------------- BN finalize ----------------
__global__ __launch_bounds__(256) void finalize_kernel(
    const float* __restrict__ psum, const float* __restrict__ psq,
    const float* __restrict__ g, const float* __restrict__ be,
    float* __restrict__ scale, float* __restrict__ shift) {
  const int ch = blockIdx.x, t = threadIdx.x;
  __shared__ float ss[256];
  __shared__ float sq[256];
  float s = 0.f, q = 0.f;
  for (int p = t; p < NBS; p += 256) {
    s += psum[(size_t)p * 128 + ch];
    q += psq[(size_t)p * 128 + ch];
  }
  ss[t] = s; sq[t] = q;
  __syncthreads();
  for (int off = 128; off >= 1; off >>= 1) {
    if (t < off) { ss[t] += ss[t + off]; sq[t] += sq[t + off]; }
    __syncthreads();
  }
  if (t == 0) {
    const float invN = 1.0f / (float)(B_ * S_ * K_);
    const float mean = ss[0] * invN;
    const float var = sq[0] * invN - mean * mean;
    const float sc = g[ch] / sqrtf(var + 1e-5f);
    scale[ch] = sc;
    shift[ch] = be[ch] - mean * sc;
  }
}

// ---------------- Final ----------------
__global__ __launch_bounds__(256) void final_kernel(
    const float* __restrict__ minbuf, const float* __restrict__ scale,
    const float* __restrict__ shift, float* __restrict__ out) {
  const int i = blockIdx.x * 256 + threadIdx.x;  // < B*S*128
  const int ch = i & 127;
  const float sc = scale[ch], sh = shift[ch];
  const float mx = out[NEWXYZ_FLOATS + i];
  const float mn = minbuf[i];
  const float v = sc * (sc >= 0.f ? mx : mn) + sh;
  out[NEWXYZ_FLOATS + i] = fmaxf(v, 0.f);
}

// ---------------- host ----------------
extern "C" void kernel_launch(void* const* d_in, const int* in_sizes, int n_in,
                              void* d_out, int out_size, void* d_ws, size_t ws_size,
                              hipStream_t stream) {
  const float* xyz = (const float*)d_in[0];
  const float* points = (const float*)d_in[1];
  const float* w0 = (const float*)d_in[2];
  const float* b0 = (const float*)d_in[3];
  const float* g0 = (const float*)d_in[4];
  const float* be0 = (const float*)d_in[5];
  const float* w1 = (const float*)d_in[6];
  const float* b1 = (const float*)d_in[7];
  const float* g1 = (const float*)d_in[8];
  const float* be1 = (const float*)d_in[9];
  const float* w2 = (const float*)d_in[10];
  const float* b2 = (const float*)d_in[11];
  const float* g2 = (const float*)d_in[12];
  const float* be2 = (const float*)d_in[13];
  float* out = (float*)d_out;
  float* newxyz = out;
  float* maxraw = out + NEWXYZ_FLOATS;

  float* ws = (float*)d_ws;
  const size_t NEED_FAST =
      (size_t)(524288 + 16384 * 2048 + 2 * NBS * 128 + 768 + NBS * 128) * 4;

  fps_kernel<<<B_, 256, 0, stream>>>(xyz, newxyz);

  if (ws_size >= NEED_FAST) {
    int* knn_idx = (int*)ws;
    float* zbuf = ws + 524288;
    float* psum = zbuf + (size_t)16384 * 2048;
    float* psq = psum + (size_t)NBS * 128;
    float* scales = psq + (size_t)NBS * 128;
    float* shifts = scales + 384;
    float* minbuf = shifts + 384;
    knn_kernel<<<NBS / 4, 256, 0, stream>>>(xyz, newxyz, knn_idx);
    passA_store_kernel<<<NBS, 256, 0, stream>>>(xyz, points, newxyz, knn_idx, w0, b0,
                                                psum, psq, zbuf);
    finalize_kernel<<<64, 256, 0, stream>>>(psum, psq, g0, be0, scales, shifts);
    passB_z_kernel<<<NBS, 256, 0, stream>>>(w1, b1, scales, shifts, psum, psq, zbuf);
    finalize_kernel<<<64, 256, 0, stream>>>(psum, psq, g1, be1, scales + 128, shifts + 128);
    passC_z_kernel<<<NBS, 256, 0, stream>>>(w2, b2, scales + 128, shifts + 128,
                                            psum, psq, maxraw, minbuf, zbuf);
    finalize_kernel<<<128, 256, 0, stream>>>(psum, psq, g2, be2, scales + 256, shifts + 256);
    final_kernel<<<(B_ * S_ * 128) / 256, 256, 0, stream>>>(minbuf, scales + 256,
                                                            shifts + 256, out);
  } else {
    int* knn_idx = (int*)ws;
    float* psum = ws + 524288;
    float* psq = psum + (size_t)NBS * 128;
    float* scales = psq + (size_t)NBS * 128;
    float* shifts = scales + 384;
    float* minbuf = shifts + 384;
    knn_kernel<<<NBS / 4, 256, 0, stream>>>(xyz, newxyz, knn_idx);
    passA_kernel<<<NBS, 256, 0, stream>>>(xyz, points, newxyz, knn_idx, w0, b0, psum, psq);
    finalize_kernel<<<64, 256, 0, stream>>>(psum, psq, g0, be0, scales, shifts);
    passB_kernel<<<NBS, 256, 0, stream>>>(xyz, points, newxyz, knn_idx, w0, b0, w1, b1,
                                          scales, shifts, psum, psq);
    finalize_kernel<<<64, 256, 0, stream>>>(psum, psq, g1, be1, scales + 128, shifts + 128);
    passC_kernel<<<NBS, 256, 0, stream>>>(xyz, points, newxyz, knn_idx, w0, b0, w1, b1, w2, b2,
                                          scales, shifts, psum, psq, maxraw, minbuf);
    finalize_kernel<<<128, 256, 0, stream>>>(psum, psq, g2, be2, scales + 256, shifts + 256);
    final_kernel<<<(B_ * S_ * 128) / 256, 256, 0, stream>>>(minbuf, scales + 256,
                                                            shifts + 256, out);
  }
}